// Round 1
// baseline (316.224 us; speedup 1.0000x reference)
//
#include <hip/hip_runtime.h>
#include <hip/hip_bf16.h>

// Problem constants (from reference setup_inputs / module constants)
#define OUT_H 14
#define OUT_W 14
#define N_IMG 4
#define C_CH  256
#define SRC_H 200
#define SRC_W 304
#define M_ROI 1024

// Split each roi's work across SPLIT blocks for occupancy.
#define SPLIT 4
#define ELEMS_PER_ROI (C_CH * OUT_H * OUT_W)          // 50176
#define ELEMS_PER_BLOCK (ELEMS_PER_ROI / SPLIT)       // 12544
#define ITERS (ELEMS_PER_BLOCK / 256)                 // 49

__global__ __launch_bounds__(256) void roi_crop_kernel(
    const float* __restrict__ src,
    const float* __restrict__ rois,
    float* __restrict__ out)
{
    const int m    = blockIdx.x / SPLIT;
    const int part = blockIdx.x % SPLIT;
    const int t    = threadIdx.x;

    __shared__ int   s_row0[OUT_H];
    __shared__ int   s_row1[OUT_H];
    __shared__ float s_wy[OUT_H];
    __shared__ int   s_col0[OUT_W];
    __shared__ int   s_col1[OUT_W];
    __shared__ float s_wx[OUT_W];
    __shared__ int   s_b;

    if (t < OUT_H + OUT_W) {
        // Load + adjust roi (redundantly in 28 threads; trivial cost).
        float bf = rois[m * 5 + 0];
        float x1 = rois[m * 5 + 1];
        float y1 = rois[m * 5 + 2];
        float x2 = rois[m * 5 + 3];
        float y2 = rois[m * 5 + 4];

        // KEEP_AR, _AR = OUT_W/OUT_H = 1.0
        float h  = y2 - y1 + 1.0f;
        float w  = x2 - x1 + 1.0f;
        float ew = (h - w) * 0.5f;
        float eh = (w - h) * 0.5f;
        if (ew > 0.0f) { x1 -= ew; x2 += ew; }
        else           { y1 -= eh; y2 += eh; }

        // EXTEND_RATIO = 0.1 -> each side extends by size * 0.05
        float sw = x2 - x1 + 1.0f;
        float sh = y2 - y1 + 1.0f;
        x1 -= sw * 0.05f; x2 += sw * 0.05f;
        y1 -= sh * 0.05f; y2 += sh * 0.05f;

        if (t < OUT_H) {
            float ty = (float)t / (float)(OUT_H - 1);
            float ys = y1 + (y2 - y1) * ty;
            ys = fminf(fmaxf(ys, 0.0f), (float)(SRC_H - 1));
            float y0f = floorf(ys);
            int   y0  = (int)y0f;
            int   y1i = min(y0 + 1, SRC_H - 1);
            s_row0[t] = y0  * SRC_W;
            s_row1[t] = y1i * SRC_W;
            s_wy[t]   = ys - y0f;
        } else {
            int i = t - OUT_H;
            float tx = (float)i / (float)(OUT_W - 1);
            float xs = x1 + (x2 - x1) * tx;
            xs = fminf(fmaxf(xs, 0.0f), (float)(SRC_W - 1));
            float x0f = floorf(xs);
            int   x0  = (int)x0f;
            int   x1i = min(x0 + 1, SRC_W - 1);
            s_col0[i] = x0;
            s_col1[i] = x1i;
            s_wx[i]   = xs - x0f;
        }
        if (t == 0) s_b = (int)bf;
    }
    __syncthreads();

    const int b = s_b;
    const float* __restrict__ srcB = src + (size_t)b * (C_CH * SRC_H * SRC_W);
    float* __restrict__ outM = out + (size_t)m * ELEMS_PER_ROI;

    const int flat_base = part * ELEMS_PER_BLOCK;

#pragma unroll 1
    for (int k = 0; k < ITERS; ++k) {
        unsigned flat = (unsigned)(flat_base + t + k * 256);
        unsigned c    = flat / 196u;              // magic-mul
        unsigned pos  = flat - c * 196u;
        unsigned oy   = pos / 14u;
        unsigned ox   = pos - oy * 14u;

        const float* __restrict__ sc = srcB + (size_t)c * (SRC_H * SRC_W);
        int   r0 = s_row0[oy];
        int   r1 = s_row1[oy];
        int   c0 = s_col0[ox];
        int   c1 = s_col1[ox];
        float wy = s_wy[oy];
        float wx = s_wx[ox];

        float v00 = sc[r0 + c0];
        float v01 = sc[r0 + c1];
        float v10 = sc[r1 + c0];
        float v11 = sc[r1 + c1];

        float top = v00 + (v01 - v00) * wx;
        float bot = v10 + (v11 - v10) * wx;
        outM[flat] = top + (bot - top) * wy;
    }
}

extern "C" void kernel_launch(void* const* d_in, const int* in_sizes, int n_in,
                              void* d_out, int out_size, void* d_ws, size_t ws_size,
                              hipStream_t stream)
{
    const float* src  = (const float*)d_in[0];
    const float* rois = (const float*)d_in[1];
    float* out = (float*)d_out;

    dim3 grid(M_ROI * SPLIT);
    dim3 block(256);
    roi_crop_kernel<<<grid, block, 0, stream>>>(src, rois, out);
}